// Round 1
// baseline (1088.570 us; speedup 1.0000x reference)
//
#include <hip/hip_runtime.h>
#include <hip/hip_bf16.h>
#include <cstdint>
#include <cstddef>

// Problem dims
#define BATCH 8192
#define DIN   2048
#define HID   2048
#define KDIM  4096   // D + H
#define NDIM  8192   // 4*H
#define MDIM  8192   // batch
#define BH    16777216  // BATCH*HID

typedef unsigned short u16;
typedef __bf16 bf16x8 __attribute__((ext_vector_type(8)));
typedef float  f32x4  __attribute__((ext_vector_type(4)));

// ---------- helpers ----------
__device__ __forceinline__ u16 f2bf(float f) {
    union { float f; unsigned u; } a; a.f = f;
    unsigned u = a.u;
    unsigned r = u + 0x7FFFu + ((u >> 16) & 1u);   // RNE
    return (u16)(r >> 16);
}
__device__ __forceinline__ float lo16(unsigned v) {
    union { unsigned u; float f; } a; a.u = v << 16; return a.f;
}
__device__ __forceinline__ float hi16(unsigned v) {
    union { unsigned u; float f; } a; a.u = v & 0xFFFF0000u; return a.f;
}
__device__ __forceinline__ void unpack8(uint4 p, float* f) {
    f[0] = lo16(p.x); f[1] = hi16(p.x);
    f[2] = lo16(p.y); f[3] = hi16(p.y);
    f[4] = lo16(p.z); f[5] = hi16(p.z);
    f[6] = lo16(p.w); f[7] = hi16(p.w);
}
__device__ __forceinline__ float sigm(float x) {
    return 1.0f / (1.0f + __expf(-x));
}
__device__ __forceinline__ float tanh_fast(float x) {
    // tanh(x) = 1 - 2/(exp(2x)+1); correct limits via inf handling
    return 1.0f - 2.0f / (__expf(2.0f * x) + 1.0f);
}
__device__ __forceinline__ void async16(const void* g, void* lds) {
    __builtin_amdgcn_global_load_lds(
        (const __attribute__((address_space(1))) void*)g,
        (__attribute__((address_space(3))) void*)lds,
        16, 0, 0);
}

// ---------- 1. cast/pack A = [x | h0] -> bf16 [8192, 4096] ----------
__global__ __launch_bounds__(256) void cast_A_kernel(
    const float* __restrict__ x, const float* __restrict__ h0,
    u16* __restrict__ Abf)
{
    size_t i8 = ((size_t)blockIdx.x * 256 + threadIdx.x) * 8;
    size_t row = i8 >> 12;            // / 4096
    int col = (int)(i8 & 4095);
    const float* src = (col < DIN) ? (x + row * DIN + col)
                                   : (h0 + row * HID + (col - DIN));
    float4 v0 = ((const float4*)src)[0];
    float4 v1 = ((const float4*)src)[1];
    uint4 o;
    o.x = (unsigned)f2bf(v0.x) | ((unsigned)f2bf(v0.y) << 16);
    o.y = (unsigned)f2bf(v0.z) | ((unsigned)f2bf(v0.w) << 16);
    o.z = (unsigned)f2bf(v1.x) | ((unsigned)f2bf(v1.y) << 16);
    o.w = (unsigned)f2bf(v1.z) | ((unsigned)f2bf(v1.w) << 16);
    *(uint4*)(Abf + i8) = o;
}

// ---------- 2. cast/pack W = [Wx | Wh] (gate order i,f,g,o) -> bf16 [8192, 4096] ----------
__global__ __launch_bounds__(256) void cast_W_kernel(
    const float* __restrict__ Wii, const float* __restrict__ Wif,
    const float* __restrict__ Wig, const float* __restrict__ Wio,
    const float* __restrict__ Whi, const float* __restrict__ Whf,
    const float* __restrict__ Whg, const float* __restrict__ Who,
    u16* __restrict__ Wbf)
{
    size_t i8 = ((size_t)blockIdx.x * 256 + threadIdx.x) * 8;
    size_t n = i8 >> 12;              // output row in [0, 8192)
    int k = (int)(i8 & 4095);
    int gate = (int)(n >> 11);        // 0..3 : i,f,g,o
    size_t h = n & 2047;
    const float* src;
    if (k < DIN) {
        const float* W = (gate == 0) ? Wii : (gate == 1) ? Wif : (gate == 2) ? Wig : Wio;
        src = W + h * DIN + k;
    } else {
        const float* W = (gate == 0) ? Whi : (gate == 1) ? Whf : (gate == 2) ? Whg : Who;
        src = W + h * HID + (k - DIN);
    }
    float4 v0 = ((const float4*)src)[0];
    float4 v1 = ((const float4*)src)[1];
    uint4 o;
    o.x = (unsigned)f2bf(v0.x) | ((unsigned)f2bf(v0.y) << 16);
    o.y = (unsigned)f2bf(v0.z) | ((unsigned)f2bf(v0.w) << 16);
    o.z = (unsigned)f2bf(v1.x) | ((unsigned)f2bf(v1.y) << 16);
    o.w = (unsigned)f2bf(v1.z) | ((unsigned)f2bf(v1.w) << 16);
    *(uint4*)(Wbf + i8) = o;
}

// ---------- 3. GEMM: C[m,n] = sum_k A[m,k] * W[n,k], bf16 in/out, fp32 acc ----------
// m97-structure: 128x128 tile, BK=32, 4 waves (2x2), each wave 64x64 via 4x4 MFMA grid.
__global__ __launch_bounds__(256) void gemm_bt_kernel(
    const u16* __restrict__ A,    // [8192, 4096]
    const u16* __restrict__ W,    // [8192, 4096]
    u16* __restrict__ C)          // [8192, 8192] bf16
{
    __shared__ u16 As[128 * 32];
    __shared__ u16 Bs[128 * 32];

    const int tid  = threadIdx.x;
    const int lane = tid & 63;
    const int wave = tid >> 6;
    const int wm   = wave & 1;        // wave row
    const int wn   = wave >> 1;       // wave col
    const int quad = lane >> 4;
    const int l16  = lane & 15;

    const size_t m0 = (size_t)blockIdx.y * 128;
    const size_t n0 = (size_t)blockIdx.x * 128;

    f32x4 acc[4][4];
    #pragma unroll
    for (int i = 0; i < 4; ++i)
        #pragma unroll
        for (int j = 0; j < 4; ++j)
            acc[i][j] = (f32x4){0.f, 0.f, 0.f, 0.f};

    for (int k0 = 0; k0 < KDIM; k0 += 32) {
        #pragma unroll
        for (int j = 0; j < 2; ++j) {
            int s   = j * 256 + tid;      // segment id 0..511
            int row = s >> 2;             // tile row 0..127
            int cs  = s & 3;              // 16B col segment
            const u16* ga = A + (m0 + row) * (size_t)KDIM + k0 + cs * 8;
            const u16* gb = W + (n0 + row) * (size_t)KDIM + k0 + cs * 8;
            async16(ga, (char*)As + (size_t)s * 16);
            async16(gb, (char*)Bs + (size_t)s * 16);
        }
        __syncthreads();

        bf16x8 af[4], bfr[4];
        #pragma unroll
        for (int mi = 0; mi < 4; ++mi)
            af[mi] = *(const bf16x8*)(As + (wm * 64 + mi * 16 + l16) * 32 + quad * 8);
        #pragma unroll
        for (int ni = 0; ni < 4; ++ni)
            bfr[ni] = *(const bf16x8*)(Bs + (wn * 64 + ni * 16 + l16) * 32 + quad * 8);

        #pragma unroll
        for (int mi = 0; mi < 4; ++mi)
            #pragma unroll
            for (int ni = 0; ni < 4; ++ni)
                acc[mi][ni] = __builtin_amdgcn_mfma_f32_16x16x32_bf16(
                    af[mi], bfr[ni], acc[mi][ni], 0, 0, 0);

        __syncthreads();
    }

    // Epilogue: C/D layout col=lane&15, row=quad*4+reg
    #pragma unroll
    for (int mi = 0; mi < 4; ++mi) {
        #pragma unroll
        for (int ni = 0; ni < 4; ++ni) {
            size_t col = n0 + wn * 64 + ni * 16 + l16;
            #pragma unroll
            for (int r = 0; r < 4; ++r) {
                size_t row = m0 + wm * 64 + mi * 16 + quad * 4 + r;
                C[row * (size_t)NDIM + col] = f2bf(acc[mi][ni][r]);
            }
        }
    }
}

// ---------- 4. LSTM elementwise epilogue ----------
__global__ __launch_bounds__(256) void lstm_epilogue_kernel(
    const u16* __restrict__ gates,     // [8192, 8192] bf16 (i,f,g,o blocks of 2048)
    const float* __restrict__ c0,
    const float* __restrict__ bii, const float* __restrict__ bhi,
    const float* __restrict__ bif, const float* __restrict__ bhf,
    const float* __restrict__ big, const float* __restrict__ bhg,
    const float* __restrict__ bio, const float* __restrict__ bho,
    float* __restrict__ out)
{
    size_t i8 = ((size_t)blockIdx.x * 256 + threadIdx.x) * 8;   // over B*H
    size_t m = i8 >> 11;
    int h = (int)(i8 & 2047);
    const u16* grow = gates + m * (size_t)NDIM;

    float gi[8], gf[8], gg[8], go[8];
    unpack8(*(const uint4*)(grow + h),        gi);
    unpack8(*(const uint4*)(grow + 2048 + h), gf);
    unpack8(*(const uint4*)(grow + 4096 + h), gg);
    unpack8(*(const uint4*)(grow + 6144 + h), go);

    float c0v[8];
    *(float4*)(c0v)     = *(const float4*)(c0 + m * HID + h);
    *(float4*)(c0v + 4) = *(const float4*)(c0 + m * HID + h + 4);

    float hbuf[8], cbuf[8];
    #pragma unroll
    for (int e = 0; e < 8; ++e) {
        float vi = sigm(gi[e] + bii[h + e] + bhi[h + e]);
        float vf = sigm(gf[e] + bif[h + e] + bhf[h + e]);
        float vg = tanh_fast(gg[e] + big[h + e] + bhg[h + e]);
        float vo = sigm(go[e] + bio[h + e] + bho[h + e]);
        float c  = vf * c0v[e] + vi * vg;
        cbuf[e] = c;
        hbuf[e] = vo * tanh_fast(c);
    }
    float* oh = out + m * HID + h;
    float* oc = out + BH + m * HID + h;
    *(float4*)(oh)     = *(float4*)(hbuf);
    *(float4*)(oh + 4) = *(float4*)(hbuf + 4);
    *(float4*)(oc)     = *(float4*)(cbuf);
    *(float4*)(oc + 4) = *(float4*)(cbuf + 4);
}

// ---------- launch ----------
extern "C" void kernel_launch(void* const* d_in, const int* in_sizes, int n_in,
                              void* d_out, int out_size, void* d_ws, size_t ws_size,
                              hipStream_t stream) {
    const float* x   = (const float*)d_in[0];
    const float* h0  = (const float*)d_in[1];
    const float* c0  = (const float*)d_in[2];
    const float* Wii = (const float*)d_in[3];  const float* bii = (const float*)d_in[4];
    const float* Wif = (const float*)d_in[5];  const float* bif = (const float*)d_in[6];
    const float* Wig = (const float*)d_in[7];  const float* big = (const float*)d_in[8];
    const float* Wio = (const float*)d_in[9];  const float* bio = (const float*)d_in[10];
    const float* Whi = (const float*)d_in[11]; const float* bhi = (const float*)d_in[12];
    const float* Whf = (const float*)d_in[13]; const float* bhf = (const float*)d_in[14];
    const float* Whg = (const float*)d_in[15]; const float* bhg = (const float*)d_in[16];
    const float* Who = (const float*)d_in[17]; const float* bho = (const float*)d_in[18];
    float* out = (float*)d_out;

    // workspace layout: Abf 64MiB | Wbf 64MiB | gates 128MiB = 256MiB total
    u16* Abf   = (u16*)d_ws;
    u16* Wbf   = Abf + (size_t)MDIM * KDIM;
    u16* gates = Wbf + (size_t)NDIM * KDIM;

    cast_A_kernel<<<16384, 256, 0, stream>>>(x, h0, Abf);
    cast_W_kernel<<<16384, 256, 0, stream>>>(Wii, Wif, Wig, Wio, Whi, Whf, Whg, Who, Wbf);
    gemm_bt_kernel<<<dim3(64, 64), 256, 0, stream>>>(Abf, Wbf, gates);
    lstm_epilogue_kernel<<<8192, 256, 0, stream>>>(gates, c0,
        bii, bhi, bif, bhf, big, bhg, bio, bho, out);
}